// Round 4
// baseline (1169.860 us; speedup 1.0000x reference)
//
#include <hip/hip_runtime.h>
#include <hip/hip_bf16.h>

#define N_NODES 100000
#define N_EDGES 1600000
#define SLOPE_ 0.2f
#define NBK 196      // row buckets of 512
#define BCAP 9216    // bucket capacity (mean 8192 + 11 sigma)
#define NCB 25       // col buckets (col>>12), 25*4096 >= 100000
#define KEYS (512 * NCB)

typedef __attribute__((ext_vector_type(8))) short bf16x8;
typedef __attribute__((ext_vector_type(4))) float f32x4;

__device__ __forceinline__ short f2bf(float f) {
    __hip_bfloat16 h = __float2bfloat16(f);
    return *reinterpret_cast<short*>(&h);
}
__device__ __forceinline__ float bflo(unsigned u) { return __uint_as_float(u << 16); }
__device__ __forceinline__ float bfhi(unsigned u) { return __uint_as_float(u & 0xFFFF0000u); }
__device__ __forceinline__ float bf2f(short s) {
    return __uint_as_float(((unsigned)(unsigned short)s) << 16);
}

// ---------------- CSR build, bucketed ----------------
// passA: bin edges by row-bucket (row>>9). Only 196 dense write fronts ->
// write amplification ~1 (vs 100K fronts in a by-row scatter).

__global__ void passA_k(const int* __restrict__ row, const int* __restrict__ col,
                        const float* __restrict__ ew, int* __restrict__ cur,
                        int2* __restrict__ binned) {
    int e = blockIdx.x * 256 + threadIdx.x;  // grid = E/256 exactly
    int r = row[e], c = col[e];
    int b = r >> 9, lr = r & 511;
    int p = atomicAdd(&cur[b], 1);
    if (p < BCAP)
        binned[(size_t)b * BCAP + p] = make_int2((lr << 17) | c, __float_as_int(ew[e]));
}

// passB: one block per bucket. LDS counting sort by key = localrow*NCB + col>>12.
// Emits final cw (writes within a 64KB window -> L2-absorbed) and row_ptr.

__global__ void __launch_bounds__(512) passB_k(const int2* __restrict__ binned,
                                               const int* __restrict__ cur,
                                               int2* __restrict__ cw,
                                               int* __restrict__ row_ptr) {
    __shared__ int hist[KEYS];
    __shared__ int offs[KEYS];
    __shared__ int ssum[512];
    __shared__ int bexc[256];
    int t = threadIdx.x, b = blockIdx.x;
    const int2* src = binned + (size_t)b * BCAP;
    int cnt = cur[b];
    if (cnt > BCAP) cnt = BCAP;

    // exclusive scan of bucket counts -> global base of this bucket
    if (t < 256) bexc[t] = (t < NBK) ? min(cur[t], BCAP) : 0;
    __syncthreads();
    for (int off = 1; off < 256; off <<= 1) {
        int v = (t < 256 && t >= off) ? bexc[t - off] : 0;
        __syncthreads();
        if (t < 256) bexc[t] += v;
        __syncthreads();
    }
    int gbase = bexc[b] - cnt;

    for (int i = t; i < KEYS; i += 512) hist[i] = 0;
    __syncthreads();

    // phase 1: histogram keys
    for (int i = t; i < cnt; i += 512) {
        int2 v = src[i];
        int c = v.x & 0x1FFFF, lr = v.x >> 17;
        atomicAdd(&hist[lr * NCB + (c >> 12)], 1);
    }
    __syncthreads();

    // scan: thread t owns localrow t's NCB keys
    int loc[NCB];
    int tot = 0;
#pragma unroll
    for (int j = 0; j < NCB; j++) {
        loc[j] = tot;
        tot += hist[t * NCB + j];
    }
    ssum[t] = tot;
    __syncthreads();
    for (int off = 1; off < 512; off <<= 1) {
        int v = (t >= off) ? ssum[t - off] : 0;
        __syncthreads();
        ssum[t] += v;
        __syncthreads();
    }
    int base = ssum[t] - tot;
#pragma unroll
    for (int j = 0; j < NCB; j++) offs[t * NCB + j] = base + loc[j];

    // row_ptr: start of global row (b*512 + t); entry N gets E.
    int grow = b * 512 + t;
    if (grow <= N_NODES) row_ptr[grow] = gbase + base;
    __syncthreads();

    // phase 2: scatter into final CSR (64KB destination window)
    for (int i = t; i < cnt; i += 512) {
        int2 v = src[i];
        int c = v.x & 0x1FFFF, lr = v.x >> 17;
        int p = gbase + atomicAdd(&offs[lr * NCB + (c >> 12)], 1);
        cw[p] = make_int2(c, v.y);
    }
}

// ---------------- weight prep: Wt[n][k] = bf16(W[k][n]) ----------------

__global__ void prep_k(const float* __restrict__ W1, const float* __restrict__ W2,
                       short* __restrict__ Wt1, short* __restrict__ Wt2) {
    int i = blockIdx.x * 256 + threadIdx.x;
    if (i < 128 * 256) {
        int n = i >> 8, k = i & 255;
        Wt1[i] = f2bf(W1[k * 128 + n]);
    }
    int j = i - 128 * 256;
    if (j >= 0 && j < 64 * 128) {
        int n = j >> 7, k = j & 127;
        Wt2[j] = f2bf(W2[k * 64 + n]);
    }
}

// ---------------- MFMA GEMM: out[M][COLS](bf16) = A[M][K] @ W[K][COLS] ----------------

template <int K, int COLS, bool ABF16>
__global__ void gemm_mfma(const void* __restrict__ Ap, const short* __restrict__ Wt,
                          short* __restrict__ out, int M) {
    constexpr int NT = COLS / 16;
    int l = threadIdx.x & 63;
    int wv = threadIdx.x >> 6;
    int row0 = blockIdx.x * 64 + wv * 16;
    int ln = l & 15, g = l >> 4;
    int arow = row0 + ln;
    bool rowok = arow < M;
    f32x4 acc[NT];
#pragma unroll
    for (int t = 0; t < NT; t++) acc[t] = (f32x4){0.f, 0.f, 0.f, 0.f};

    for (int k0 = 0; k0 < K; k0 += 32) {
        int kk = k0 + g * 8;
        bf16x8 af = {};
        if constexpr (ABF16) {
            if (rowok) af = *(const bf16x8*)((const short*)Ap + (size_t)arow * K + kk);
        } else {
            if (rowok) {
                const float* ap = (const float*)Ap + (size_t)arow * K + kk;
                float4 u0 = *(const float4*)ap;
                float4 u1 = *(const float4*)(ap + 4);
                af[0] = f2bf(u0.x); af[1] = f2bf(u0.y);
                af[2] = f2bf(u0.z); af[3] = f2bf(u0.w);
                af[4] = f2bf(u1.x); af[5] = f2bf(u1.y);
                af[6] = f2bf(u1.z); af[7] = f2bf(u1.w);
            }
        }
#pragma unroll
        for (int nt = 0; nt < NT; nt++) {
            bf16x8 bfr = *(const bf16x8*)(Wt + (size_t)(nt * 16 + ln) * K + kk);
            acc[nt] = __builtin_amdgcn_mfma_f32_16x16x32_bf16(af, bfr, acc[nt], 0, 0, 0);
        }
    }
#pragma unroll
    for (int nt = 0; nt < NT; nt++) {
#pragma unroll
        for (int r = 0; r < 4; r++) {
            int orow = row0 + g * 4 + r;
            if (orow < M) out[(size_t)orow * COLS + nt * 16 + ln] = f2bf(acc[nt][r]);
        }
    }
}

// ---------------- pull-SpMM: cooperative metadata load + 4x unrolled gathers ----------------

template <int D, bool DROP>
__global__ void spmm_bf(const int* __restrict__ row_ptr, const int2* __restrict__ cw,
                        const short* __restrict__ h,
                        const float* __restrict__ bias, const float* __restrict__ mask,
                        short* __restrict__ out, int n) {
    int wid = (int)((blockIdx.x * (size_t)blockDim.x + threadIdx.x) >> 6);
    int lane = threadIdx.x & 63;
    if (wid >= n) return;
    int s = row_ptr[wid], e = row_ptr[wid + 1];
    float ax = 0.f, ay = 0.f;
    int base = s;
    while (base < e) {
        int m = e - base;
        if (m > 64) m = 64;
        int2 cwv = (lane < m) ? cw[base + lane] : make_int2(0, 0);
        int j = 0;
        for (; j + 4 <= m; j += 4) {
            int c0 = __shfl(cwv.x, j);     float w0 = __uint_as_float(__shfl(cwv.y, j));
            int c1 = __shfl(cwv.x, j + 1); float w1 = __uint_as_float(__shfl(cwv.y, j + 1));
            int c2 = __shfl(cwv.x, j + 2); float w2 = __uint_as_float(__shfl(cwv.y, j + 2));
            int c3 = __shfl(cwv.x, j + 3); float w3 = __uint_as_float(__shfl(cwv.y, j + 3));
            if (D == 128) {
                unsigned u0 = *(const unsigned*)(h + (size_t)c0 * 128 + 2 * lane);
                unsigned u1 = *(const unsigned*)(h + (size_t)c1 * 128 + 2 * lane);
                unsigned u2 = *(const unsigned*)(h + (size_t)c2 * 128 + 2 * lane);
                unsigned u3 = *(const unsigned*)(h + (size_t)c3 * 128 + 2 * lane);
                ax += w0 * bflo(u0); ay += w0 * bfhi(u0);
                ax += w1 * bflo(u1); ay += w1 * bfhi(u1);
                ax += w2 * bflo(u2); ay += w2 * bfhi(u2);
                ax += w3 * bflo(u3); ay += w3 * bfhi(u3);
            } else {
                float v0 = bf2f(h[(size_t)c0 * 64 + lane]);
                float v1 = bf2f(h[(size_t)c1 * 64 + lane]);
                float v2 = bf2f(h[(size_t)c2 * 64 + lane]);
                float v3 = bf2f(h[(size_t)c3 * 64 + lane]);
                ax += w0 * v0 + w1 * v1 + w2 * v2 + w3 * v3;
            }
        }
        for (; j < m; j++) {
            int c0 = __shfl(cwv.x, j);
            float w0 = __uint_as_float(__shfl(cwv.y, j));
            if (D == 128) {
                unsigned u0 = *(const unsigned*)(h + (size_t)c0 * 128 + 2 * lane);
                ax += w0 * bflo(u0); ay += w0 * bfhi(u0);
            } else {
                ax += w0 * bf2f(h[(size_t)c0 * 64 + lane]);
            }
        }
        base += m;
    }
    if (D == 128) {
        float2 b = *(const float2*)(bias + 2 * lane);
        float ox = ax + b.x, oy = ay + b.y;
        ox = ox > 0.f ? ox : SLOPE_ * ox;
        oy = oy > 0.f ? oy : SLOPE_ * oy;
        if (DROP) {
            float2 m2 = *(const float2*)(mask + (size_t)wid * 128 + 2 * lane);
            ox *= m2.x;
            oy *= m2.y;
        }
        unsigned ov = (unsigned)(unsigned short)f2bf(ox) |
                      ((unsigned)(unsigned short)f2bf(oy) << 16);
        *(unsigned*)(out + (size_t)wid * 128 + 2 * lane) = ov;
    } else {
        float o = ax + bias[lane];
        o = o > 0.f ? o : SLOPE_ * o;
        out[(size_t)wid * 64 + lane] = f2bf(o);
    }
}

// ---------------- fused classifier: out = lrelu(h@W3+b3)@W4 + b4 (h bf16) ----------------

__global__ void clf_k(const short* __restrict__ h, const float* __restrict__ W3,
                      const float* __restrict__ b3, const float* __restrict__ W4,
                      const float* __restrict__ b4, float* __restrict__ out) {
    __shared__ float W3s[64][32];
    __shared__ float W4s[32][16];
    __shared__ float b3s[32], b4s[16];
    __shared__ float hs[32][64];
    __shared__ float t4[32][33];  // pad
    int t = threadIdx.x;
    for (int l = t; l < 64 * 32; l += 256) W3s[l / 32][l % 32] = W3[l];
    for (int l = t; l < 32 * 16; l += 256) W4s[l / 16][l % 16] = W4[l];
    if (t < 32) b3s[t] = b3[t];
    if (t < 16) b4s[t] = b4[t];
    int row0 = blockIdx.x * 32;
    {
        bf16x8 v = *(const bf16x8*)(h + (size_t)row0 * 64 + t * 8);
        int r = t >> 3, c0 = (t & 7) << 3;
#pragma unroll
        for (int j = 0; j < 8; j++) hs[r][c0 + j] = bf2f(v[j]);
    }
    __syncthreads();
    for (int l = t; l < 1024; l += 256) {
        int r = l / 32, c = l % 32;
        float a = b3s[c];
#pragma unroll 8
        for (int k = 0; k < 64; k++) a += hs[r][k] * W3s[k][c];
        t4[r][c] = a > 0.f ? a : SLOPE_ * a;
    }
    __syncthreads();
    for (int l = t; l < 512; l += 256) {
        int r = l / 16, c = l % 16;
        float a = b4s[c];
#pragma unroll
        for (int k = 0; k < 32; k++) a += t4[r][k] * W4s[k][c];
        out[(size_t)(row0 + r) * 16 + c] = a;
    }
}

// ---------------- launch ----------------

extern "C" void kernel_launch(void* const* d_in, const int* in_sizes, int n_in,
                              void* d_out, int out_size, void* d_ws, size_t ws_size,
                              hipStream_t stream) {
    const float* x = (const float*)d_in[0];
    const int* row = (const int*)d_in[1];
    const int* col = (const int*)d_in[2];
    const float* ew = (const float*)d_in[3];
    const float* W1 = (const float*)d_in[4];
    const float* b1 = (const float*)d_in[5];
    const float* W2 = (const float*)d_in[6];
    const float* b2 = (const float*)d_in[7];
    const float* W3 = (const float*)d_in[8];
    const float* b3 = (const float*)d_in[9];
    const float* W4 = (const float*)d_in[10];
    const float* b4 = (const float*)d_in[11];
    const float* mask = (const float*)d_in[12];
    float* out = (float*)d_out;

    const int N = N_NODES, E = N_EDGES;

    short* h0 = (short*)d_ws;              // N*128 bf16 (gemm1 out)
    short* h1 = h0 + (size_t)N * 128;      // N*128 bf16 (spmm1 out)
    short* h2 = h1 + (size_t)N * 128;      // N*64  bf16 (gemm2 out)
    short* h3 = h2 + (size_t)N * 64;       // N*64  bf16 (spmm2 out)
    short* Wt1 = h3 + (size_t)N * 64;      // 128*256 bf16
    short* Wt2 = Wt1 + 128 * 256;          // 64*128 bf16
    int* row_ptr = (int*)(Wt2 + 64 * 128); // N+1
    int* cur = row_ptr + N + 1;            // NBK
    int2* cw = (int2*)(cur + NBK + 3);     // E int2 (8B-aligned by layout)
    int2* binned = (int2*)h0;              // NBK*BCAP int2 = 14.5MB, aliases h0
                                           // (consumed by passB before gemm1 writes h0)

    hipMemsetAsync(cur, 0, NBK * sizeof(int), stream);
    passA_k<<<E / 256, 256, 0, stream>>>(row, col, ew, cur, binned);
    passB_k<<<NBK, 512, 0, stream>>>(binned, cur, cw, row_ptr);
    prep_k<<<160, 256, 0, stream>>>(W1, W2, Wt1, Wt2);

    gemm_mfma<256, 128, false><<<(N + 63) / 64, 256, 0, stream>>>(x, Wt1, h0, N);
    spmm_bf<128, true><<<(N + 3) / 4, 256, 0, stream>>>(row_ptr, cw, h0, b1, mask, h1, N);
    gemm_mfma<128, 64, true><<<(N + 63) / 64, 256, 0, stream>>>(h1, Wt2, h2, N);
    spmm_bf<64, false><<<(N + 3) / 4, 256, 0, stream>>>(row_ptr, cw, h2, b2, nullptr, h3, N);
    clf_k<<<N / 32, 256, 0, stream>>>(h3, W3, b3, W4, b4, out);
}

// Round 5
// 310.727 us; speedup vs baseline: 3.7649x; 3.7649x over previous
//
#include <hip/hip_runtime.h>
#include <hip/hip_bf16.h>

#define N_NODES 100000
#define N_EDGES 1600000
#define SLOPE_ 0.2f
#define NBK 196      // row buckets of 512
#define BCAP 9216    // bucket capacity (mean 8192 + 11 sigma)
#define NCB 25       // col buckets (col>>12), 25*4096 >= 100000
#define KEYS (512 * NCB)
#define BINBLK 256   // binning blocks; chunk = E/BINBLK = 6250

typedef __attribute__((ext_vector_type(8))) short bf16x8;
typedef __attribute__((ext_vector_type(4))) float f32x4;

__device__ __forceinline__ short f2bf(float f) {
    __hip_bfloat16 h = __float2bfloat16(f);
    return *reinterpret_cast<short*>(&h);
}
__device__ __forceinline__ float bflo(unsigned u) { return __uint_as_float(u << 16); }
__device__ __forceinline__ float bfhi(unsigned u) { return __uint_as_float(u & 0xFFFF0000u); }
__device__ __forceinline__ float bf2f(short s) {
    return __uint_as_float(((unsigned)(unsigned short)s) << 16);
}

// ---------------- CSR build, bucketed ----------------
// passA: bin edges by row-bucket (row>>9), block-aggregated to kill atomic
// contention: per block LDS histogram -> 1 global atomic per (block,bucket)
// (50K total, vs 1.6M in round 4) -> LDS-offset scatter. 196 dense write
// fronts -> write amplification ~1.

__global__ void passA_k(const int* __restrict__ row, const int* __restrict__ col,
                        const float* __restrict__ ew, int* __restrict__ cur,
                        int2* __restrict__ binned) {
    __shared__ int hist[NBK], base[NBK], off[NBK];
    int t = threadIdx.x;
    const int chunk = N_EDGES / BINBLK;  // 6250
    int e0 = blockIdx.x * chunk;
    for (int i = t; i < NBK; i += 256) { hist[i] = 0; off[i] = 0; }
    __syncthreads();
    for (int i = t; i < chunk; i += 256) {
        int b = row[e0 + i] >> 9;
        atomicAdd(&hist[b], 1);            // LDS atomic
    }
    __syncthreads();
    for (int i = t; i < NBK; i += 256)
        base[i] = atomicAdd(&cur[i], hist[i]);  // 196 global atomics per block
    __syncthreads();
    for (int i = t; i < chunk; i += 256) {
        int e = e0 + i;
        int r = row[e], c = col[e];
        int b = r >> 9;
        int p = base[b] + atomicAdd(&off[b], 1);  // LDS atomic
        if (p < BCAP)
            binned[(size_t)b * BCAP + p] =
                make_int2(((r & 511) << 17) | c, __float_as_int(ew[e]));
    }
}

// passB: one block per bucket. LDS counting sort by key = localrow*NCB + col>>12.
// Emits final cw (writes within a 64KB window -> L2-absorbed) and row_ptr.

__global__ void __launch_bounds__(512) passB_k(const int2* __restrict__ binned,
                                               const int* __restrict__ cur,
                                               int2* __restrict__ cw,
                                               int* __restrict__ row_ptr) {
    __shared__ int hist[KEYS];
    __shared__ int offs[KEYS];
    __shared__ int ssum[512];
    __shared__ int bexc[256];
    int t = threadIdx.x, b = blockIdx.x;
    const int2* src = binned + (size_t)b * BCAP;
    int cnt = cur[b];
    if (cnt > BCAP) cnt = BCAP;

    // exclusive scan of bucket counts -> global base of this bucket
    if (t < 256) bexc[t] = (t < NBK) ? min(cur[t], BCAP) : 0;
    __syncthreads();
    for (int off2 = 1; off2 < 256; off2 <<= 1) {
        int v = (t < 256 && t >= off2) ? bexc[t - off2] : 0;
        __syncthreads();
        if (t < 256) bexc[t] += v;
        __syncthreads();
    }
    int gbase = bexc[b] - cnt;

    for (int i = t; i < KEYS; i += 512) hist[i] = 0;
    __syncthreads();

    // phase 1: histogram keys
    for (int i = t; i < cnt; i += 512) {
        int2 v = src[i];
        int c = v.x & 0x1FFFF, lr = v.x >> 17;
        atomicAdd(&hist[lr * NCB + (c >> 12)], 1);
    }
    __syncthreads();

    // scan: thread t owns localrow t's NCB keys
    int loc[NCB];
    int tot = 0;
#pragma unroll
    for (int j = 0; j < NCB; j++) {
        loc[j] = tot;
        tot += hist[t * NCB + j];
    }
    ssum[t] = tot;
    __syncthreads();
    for (int off2 = 1; off2 < 512; off2 <<= 1) {
        int v = (t >= off2) ? ssum[t - off2] : 0;
        __syncthreads();
        ssum[t] += v;
        __syncthreads();
    }
    int base = ssum[t] - tot;
#pragma unroll
    for (int j = 0; j < NCB; j++) offs[t * NCB + j] = base + loc[j];

    // row_ptr: start of global row (b*512 + t); entry N gets E.
    int grow = b * 512 + t;
    if (grow <= N_NODES) row_ptr[grow] = gbase + base;
    __syncthreads();

    // phase 2: scatter into final CSR (64KB destination window)
    for (int i = t; i < cnt; i += 512) {
        int2 v = src[i];
        int c = v.x & 0x1FFFF, lr = v.x >> 17;
        int p = gbase + atomicAdd(&offs[lr * NCB + (c >> 12)], 1);
        cw[p] = make_int2(c, v.y);
    }
}

// ---------------- weight prep: Wt[n][k] = bf16(W[k][n]) ----------------

__global__ void prep_k(const float* __restrict__ W1, const float* __restrict__ W2,
                       short* __restrict__ Wt1, short* __restrict__ Wt2) {
    int i = blockIdx.x * 256 + threadIdx.x;
    if (i < 128 * 256) {
        int n = i >> 8, k = i & 255;
        Wt1[i] = f2bf(W1[k * 128 + n]);
    }
    int j = i - 128 * 256;
    if (j >= 0 && j < 64 * 128) {
        int n = j >> 7, k = j & 127;
        Wt2[j] = f2bf(W2[k * 64 + n]);
    }
}

// ---------------- MFMA GEMM: out[M][COLS](bf16) = A[M][K] @ W[K][COLS] ----------------

template <int K, int COLS, bool ABF16>
__global__ void gemm_mfma(const void* __restrict__ Ap, const short* __restrict__ Wt,
                          short* __restrict__ out, int M) {
    constexpr int NT = COLS / 16;
    int l = threadIdx.x & 63;
    int wv = threadIdx.x >> 6;
    int row0 = blockIdx.x * 64 + wv * 16;
    int ln = l & 15, g = l >> 4;
    int arow = row0 + ln;
    bool rowok = arow < M;
    f32x4 acc[NT];
#pragma unroll
    for (int t = 0; t < NT; t++) acc[t] = (f32x4){0.f, 0.f, 0.f, 0.f};

    for (int k0 = 0; k0 < K; k0 += 32) {
        int kk = k0 + g * 8;
        bf16x8 af = {};
        if constexpr (ABF16) {
            if (rowok) af = *(const bf16x8*)((const short*)Ap + (size_t)arow * K + kk);
        } else {
            if (rowok) {
                const float* ap = (const float*)Ap + (size_t)arow * K + kk;
                float4 u0 = *(const float4*)ap;
                float4 u1 = *(const float4*)(ap + 4);
                af[0] = f2bf(u0.x); af[1] = f2bf(u0.y);
                af[2] = f2bf(u0.z); af[3] = f2bf(u0.w);
                af[4] = f2bf(u1.x); af[5] = f2bf(u1.y);
                af[6] = f2bf(u1.z); af[7] = f2bf(u1.w);
            }
        }
#pragma unroll
        for (int nt = 0; nt < NT; nt++) {
            bf16x8 bfr = *(const bf16x8*)(Wt + (size_t)(nt * 16 + ln) * K + kk);
            acc[nt] = __builtin_amdgcn_mfma_f32_16x16x32_bf16(af, bfr, acc[nt], 0, 0, 0);
        }
    }
#pragma unroll
    for (int nt = 0; nt < NT; nt++) {
#pragma unroll
        for (int r = 0; r < 4; r++) {
            int orow = row0 + g * 4 + r;
            if (orow < M) out[(size_t)orow * COLS + nt * 16 + ln] = f2bf(acc[nt][r]);
        }
    }
}

// ---------------- pull-SpMM: cooperative metadata load + 4x unrolled gathers ----------------

template <int D, bool DROP>
__global__ void spmm_bf(const int* __restrict__ row_ptr, const int2* __restrict__ cw,
                        const short* __restrict__ h,
                        const float* __restrict__ bias, const float* __restrict__ mask,
                        short* __restrict__ out, int n) {
    int wid = (int)((blockIdx.x * (size_t)blockDim.x + threadIdx.x) >> 6);
    int lane = threadIdx.x & 63;
    if (wid >= n) return;
    int s = row_ptr[wid], e = row_ptr[wid + 1];
    float ax = 0.f, ay = 0.f;
    int base = s;
    while (base < e) {
        int m = e - base;
        if (m > 64) m = 64;
        int2 cwv = (lane < m) ? cw[base + lane] : make_int2(0, 0);
        int j = 0;
        for (; j + 4 <= m; j += 4) {
            int c0 = __shfl(cwv.x, j);     float w0 = __uint_as_float(__shfl(cwv.y, j));
            int c1 = __shfl(cwv.x, j + 1); float w1 = __uint_as_float(__shfl(cwv.y, j + 1));
            int c2 = __shfl(cwv.x, j + 2); float w2 = __uint_as_float(__shfl(cwv.y, j + 2));
            int c3 = __shfl(cwv.x, j + 3); float w3 = __uint_as_float(__shfl(cwv.y, j + 3));
            if (D == 128) {
                unsigned u0 = *(const unsigned*)(h + (size_t)c0 * 128 + 2 * lane);
                unsigned u1 = *(const unsigned*)(h + (size_t)c1 * 128 + 2 * lane);
                unsigned u2 = *(const unsigned*)(h + (size_t)c2 * 128 + 2 * lane);
                unsigned u3 = *(const unsigned*)(h + (size_t)c3 * 128 + 2 * lane);
                ax += w0 * bflo(u0); ay += w0 * bfhi(u0);
                ax += w1 * bflo(u1); ay += w1 * bfhi(u1);
                ax += w2 * bflo(u2); ay += w2 * bfhi(u2);
                ax += w3 * bflo(u3); ay += w3 * bfhi(u3);
            } else {
                float v0 = bf2f(h[(size_t)c0 * 64 + lane]);
                float v1 = bf2f(h[(size_t)c1 * 64 + lane]);
                float v2 = bf2f(h[(size_t)c2 * 64 + lane]);
                float v3 = bf2f(h[(size_t)c3 * 64 + lane]);
                ax += w0 * v0 + w1 * v1 + w2 * v2 + w3 * v3;
            }
        }
        for (; j < m; j++) {
            int c0 = __shfl(cwv.x, j);
            float w0 = __uint_as_float(__shfl(cwv.y, j));
            if (D == 128) {
                unsigned u0 = *(const unsigned*)(h + (size_t)c0 * 128 + 2 * lane);
                ax += w0 * bflo(u0); ay += w0 * bfhi(u0);
            } else {
                ax += w0 * bf2f(h[(size_t)c0 * 64 + lane]);
            }
        }
        base += m;
    }
    if (D == 128) {
        float2 b = *(const float2*)(bias + 2 * lane);
        float ox = ax + b.x, oy = ay + b.y;
        ox = ox > 0.f ? ox : SLOPE_ * ox;
        oy = oy > 0.f ? oy : SLOPE_ * oy;
        if (DROP) {
            float2 m2 = *(const float2*)(mask + (size_t)wid * 128 + 2 * lane);
            ox *= m2.x;
            oy *= m2.y;
        }
        unsigned ov = (unsigned)(unsigned short)f2bf(ox) |
                      ((unsigned)(unsigned short)f2bf(oy) << 16);
        *(unsigned*)(out + (size_t)wid * 128 + 2 * lane) = ov;
    } else {
        float o = ax + bias[lane];
        o = o > 0.f ? o : SLOPE_ * o;
        out[(size_t)wid * 64 + lane] = f2bf(o);
    }
}

// ---------------- fused classifier: out = lrelu(h@W3+b3)@W4 + b4 (h bf16) ----------------

__global__ void clf_k(const short* __restrict__ h, const float* __restrict__ W3,
                      const float* __restrict__ b3, const float* __restrict__ W4,
                      const float* __restrict__ b4, float* __restrict__ out) {
    __shared__ float W3s[64][32];
    __shared__ float W4s[32][16];
    __shared__ float b3s[32], b4s[16];
    __shared__ float hs[32][64];
    __shared__ float t4[32][33];  // pad
    int t = threadIdx.x;
    for (int l = t; l < 64 * 32; l += 256) W3s[l / 32][l % 32] = W3[l];
    for (int l = t; l < 32 * 16; l += 256) W4s[l / 16][l % 16] = W4[l];
    if (t < 32) b3s[t] = b3[t];
    if (t < 16) b4s[t] = b4[t];
    int row0 = blockIdx.x * 32;
    {
        bf16x8 v = *(const bf16x8*)(h + (size_t)row0 * 64 + t * 8);
        int r = t >> 3, c0 = (t & 7) << 3;
#pragma unroll
        for (int j = 0; j < 8; j++) hs[r][c0 + j] = bf2f(v[j]);
    }
    __syncthreads();
    for (int l = t; l < 1024; l += 256) {
        int r = l / 32, c = l % 32;
        float a = b3s[c];
#pragma unroll 8
        for (int k = 0; k < 64; k++) a += hs[r][k] * W3s[k][c];
        t4[r][c] = a > 0.f ? a : SLOPE_ * a;
    }
    __syncthreads();
    for (int l = t; l < 512; l += 256) {
        int r = l / 16, c = l % 16;
        float a = b4s[c];
#pragma unroll
        for (int k = 0; k < 32; k++) a += t4[r][k] * W4s[k][c];
        out[(size_t)(row0 + r) * 16 + c] = a;
    }
}

// ---------------- launch ----------------

extern "C" void kernel_launch(void* const* d_in, const int* in_sizes, int n_in,
                              void* d_out, int out_size, void* d_ws, size_t ws_size,
                              hipStream_t stream) {
    const float* x = (const float*)d_in[0];
    const int* row = (const int*)d_in[1];
    const int* col = (const int*)d_in[2];
    const float* ew = (const float*)d_in[3];
    const float* W1 = (const float*)d_in[4];
    const float* b1 = (const float*)d_in[5];
    const float* W2 = (const float*)d_in[6];
    const float* b2 = (const float*)d_in[7];
    const float* W3 = (const float*)d_in[8];
    const float* b3 = (const float*)d_in[9];
    const float* W4 = (const float*)d_in[10];
    const float* b4 = (const float*)d_in[11];
    const float* mask = (const float*)d_in[12];
    float* out = (float*)d_out;

    const int N = N_NODES, E = N_EDGES;

    short* h0 = (short*)d_ws;              // N*128 bf16 (gemm1 out)
    short* h1 = h0 + (size_t)N * 128;      // N*128 bf16 (spmm1 out)
    short* h2 = h1 + (size_t)N * 128;      // N*64  bf16 (gemm2 out)
    short* h3 = h2 + (size_t)N * 64;       // N*64  bf16 (spmm2 out)
    short* Wt1 = h3 + (size_t)N * 64;      // 128*256 bf16
    short* Wt2 = Wt1 + 128 * 256;          // 64*128 bf16
    int* row_ptr = (int*)(Wt2 + 64 * 128); // N+1
    int* cur = row_ptr + N + 1;            // NBK
    int2* cw = (int2*)(cur + NBK + 3);     // E int2 (8B-aligned by layout)
    int2* binned = (int2*)h0;              // NBK*BCAP int2 = 14.5MB, aliases h0
                                           // (consumed by passB before gemm1 writes h0)

    hipMemsetAsync(cur, 0, NBK * sizeof(int), stream);
    passA_k<<<BINBLK, 256, 0, stream>>>(row, col, ew, cur, binned);
    passB_k<<<NBK, 512, 0, stream>>>(binned, cur, cw, row_ptr);
    prep_k<<<160, 256, 0, stream>>>(W1, W2, Wt1, Wt2);

    gemm_mfma<256, 128, false><<<(N + 63) / 64, 256, 0, stream>>>(x, Wt1, h0, N);
    spmm_bf<128, true><<<(N + 3) / 4, 256, 0, stream>>>(row_ptr, cw, h0, b1, mask, h1, N);
    gemm_mfma<128, 64, true><<<(N + 63) / 64, 256, 0, stream>>>(h1, Wt2, h2, N);
    spmm_bf<64, false><<<(N + 3) / 4, 256, 0, stream>>>(row_ptr, cw, h2, b2, nullptr, h3, N);
    clf_k<<<N / 32, 256, 0, stream>>>(h3, W3, b3, W4, b4, out);
}

// Round 6
// 305.489 us; speedup vs baseline: 3.8295x; 1.0171x over previous
//
#include <hip/hip_runtime.h>
#include <hip/hip_bf16.h>

#define N_NODES 100000
#define N_EDGES 1600000
#define SLOPE_ 0.2f
#define NBK 196      // row buckets of 512
#define BCAP 9216    // bucket capacity (mean 8192 + 11 sigma)
#define NCB 25       // col buckets (col>>12), 25*4096 >= 100000
#define KEYS (512 * NCB)
#define BINBLK 256   // binning blocks; chunk = E/BINBLK = 6250

typedef __attribute__((ext_vector_type(8))) short bf16x8;
typedef __attribute__((ext_vector_type(4))) float f32x4;

__device__ __forceinline__ short f2bf(float f) {
    __hip_bfloat16 h = __float2bfloat16(f);
    return *reinterpret_cast<short*>(&h);
}
__device__ __forceinline__ float bflo(unsigned u) { return __uint_as_float(u << 16); }
__device__ __forceinline__ float bfhi(unsigned u) { return __uint_as_float(u & 0xFFFF0000u); }
__device__ __forceinline__ float bf2f(short s) {
    return __uint_as_float(((unsigned)(unsigned short)s) << 16);
}

// ---------------- CSR build, bucketed ----------------
// passA: block-aggregated binning by row-bucket (row>>9): LDS histogram ->
// 1 global atomic per (block,bucket) -> LDS-offset scatter. 196 dense write
// fronts -> write amplification ~1, no global atomic contention.

__global__ void passA_k(const int* __restrict__ row, const int* __restrict__ col,
                        const float* __restrict__ ew, int* __restrict__ cur,
                        int2* __restrict__ binned) {
    __shared__ int hist[NBK], base[NBK], off[NBK];
    int t = threadIdx.x;
    const int chunk = N_EDGES / BINBLK;  // 6250
    int e0 = blockIdx.x * chunk;
    for (int i = t; i < NBK; i += 256) { hist[i] = 0; off[i] = 0; }
    __syncthreads();
    for (int i = t; i < chunk; i += 256) {
        int b = row[e0 + i] >> 9;
        atomicAdd(&hist[b], 1);            // LDS atomic
    }
    __syncthreads();
    for (int i = t; i < NBK; i += 256)
        base[i] = atomicAdd(&cur[i], hist[i]);  // 196 global atomics per block
    __syncthreads();
    for (int i = t; i < chunk; i += 256) {
        int e = e0 + i;
        int r = row[e], c = col[e];
        int b = r >> 9;
        int p = base[b] + atomicAdd(&off[b], 1);  // LDS atomic
        if (p < BCAP)
            binned[(size_t)b * BCAP + p] =
                make_int2(((r & 511) << 17) | c, __float_as_int(ew[e]));
    }
}

// passB: one block per bucket. LDS counting sort by key = localrow*NCB + col>>12.
// Emits final cw (writes within a 64KB window -> L2-absorbed) and row_ptr.

__global__ void __launch_bounds__(512) passB_k(const int2* __restrict__ binned,
                                               const int* __restrict__ cur,
                                               int2* __restrict__ cw,
                                               int* __restrict__ row_ptr) {
    __shared__ int hist[KEYS];
    __shared__ int offs[KEYS];
    __shared__ int ssum[512];
    __shared__ int bexc[256];
    int t = threadIdx.x, b = blockIdx.x;
    const int2* src = binned + (size_t)b * BCAP;
    int cnt = cur[b];
    if (cnt > BCAP) cnt = BCAP;

    // exclusive scan of bucket counts -> global base of this bucket
    if (t < 256) bexc[t] = (t < NBK) ? min(cur[t], BCAP) : 0;
    __syncthreads();
    for (int off2 = 1; off2 < 256; off2 <<= 1) {
        int v = (t < 256 && t >= off2) ? bexc[t - off2] : 0;
        __syncthreads();
        if (t < 256) bexc[t] += v;
        __syncthreads();
    }
    int gbase = bexc[b] - cnt;

    for (int i = t; i < KEYS; i += 512) hist[i] = 0;
    __syncthreads();

    // phase 1: histogram keys
    for (int i = t; i < cnt; i += 512) {
        int2 v = src[i];
        int c = v.x & 0x1FFFF, lr = v.x >> 17;
        atomicAdd(&hist[lr * NCB + (c >> 12)], 1);
    }
    __syncthreads();

    // scan: thread t owns localrow t's NCB keys
    int loc[NCB];
    int tot = 0;
#pragma unroll
    for (int j = 0; j < NCB; j++) {
        loc[j] = tot;
        tot += hist[t * NCB + j];
    }
    ssum[t] = tot;
    __syncthreads();
    for (int off2 = 1; off2 < 512; off2 <<= 1) {
        int v = (t >= off2) ? ssum[t - off2] : 0;
        __syncthreads();
        ssum[t] += v;
        __syncthreads();
    }
    int base = ssum[t] - tot;
#pragma unroll
    for (int j = 0; j < NCB; j++) offs[t * NCB + j] = base + loc[j];

    // row_ptr: start of global row (b*512 + t); entry N gets E.
    int grow = b * 512 + t;
    if (grow <= N_NODES) row_ptr[grow] = gbase + base;
    __syncthreads();

    // phase 2: scatter into final CSR (64KB destination window)
    for (int i = t; i < cnt; i += 512) {
        int2 v = src[i];
        int c = v.x & 0x1FFFF, lr = v.x >> 17;
        int p = gbase + atomicAdd(&offs[lr * NCB + (c >> 12)], 1);
        cw[p] = make_int2(c, v.y);
    }
}

// ---------------- weight prep: Wt[n][k] = bf16(W[k][n]) ----------------

__global__ void prep_k(const float* __restrict__ W1, const float* __restrict__ W2,
                       short* __restrict__ Wt1, short* __restrict__ Wt2) {
    int i = blockIdx.x * 256 + threadIdx.x;
    if (i < 128 * 256) {
        int n = i >> 8, k = i & 255;
        Wt1[i] = f2bf(W1[k * 128 + n]);
    }
    int j = i - 128 * 256;
    if (j >= 0 && j < 64 * 128) {
        int n = j >> 7, k = j & 127;
        Wt2[j] = f2bf(W2[k * 64 + n]);
    }
}

// ---------------- MFMA GEMM: out[M][COLS](bf16) = A[M][K] @ W[K][COLS] ----------------
// LDS-staged A-tile: BM rows x K, coalesced global loads, +8-short row pad
// (row stride 528B/272B -> bank slot advances 1/row -> 2-way conflict = free).
// B-fragments direct from global Wt[n][k] (L2-resident).
// Fragment math identical to round-2..5 verified kernel.

template <int K, int COLS, bool ABF16, int BM>
__global__ void gemm_mfma(const void* __restrict__ Ap, const short* __restrict__ Wt,
                          short* __restrict__ out, int M) {
    constexpr int NT = COLS / 16;
    constexpr int RF = BM / 64;          // row-frags per wave (4 waves)
    constexpr int PADK = K + 8;
    constexpr int CH = K / 8;            // 16B chunks per row
    __shared__ short As[BM * PADK];
    int t = threadIdx.x;
    int l = t & 63;
    int wv = t >> 6;
    int row0 = blockIdx.x * BM;
    int ln = l & 15, g = l >> 4;

    // stage A tile (convert fp32->bf16 if needed)
    for (int i = t; i < BM * CH; i += 256) {
        int r = i / CH, c8 = i % CH;
        int grow = row0 + r;
        if (grow > M - 1) grow = M - 1;
        bf16x8 v;
        if constexpr (ABF16) {
            v = *(const bf16x8*)((const short*)Ap + (size_t)grow * K + c8 * 8);
        } else {
            const float* ap = (const float*)Ap + (size_t)grow * K + c8 * 8;
            float4 u0 = *(const float4*)ap;
            float4 u1 = *(const float4*)(ap + 4);
            v[0] = f2bf(u0.x); v[1] = f2bf(u0.y);
            v[2] = f2bf(u0.z); v[3] = f2bf(u0.w);
            v[4] = f2bf(u1.x); v[5] = f2bf(u1.y);
            v[6] = f2bf(u1.z); v[7] = f2bf(u1.w);
        }
        *(bf16x8*)(As + (size_t)r * PADK + c8 * 8) = v;
    }
    __syncthreads();

    int wrow = wv * (BM / 4);  // wave's base row within tile
    f32x4 acc[RF][NT];
#pragma unroll
    for (int rf = 0; rf < RF; rf++)
#pragma unroll
        for (int nt = 0; nt < NT; nt++) acc[rf][nt] = (f32x4){0.f, 0.f, 0.f, 0.f};

#pragma unroll
    for (int k0 = 0; k0 < K; k0 += 32) {
        int kk = k0 + g * 8;
        bf16x8 af[RF];
#pragma unroll
        for (int rf = 0; rf < RF; rf++)
            af[rf] = *(const bf16x8*)(As + (size_t)(wrow + rf * 16 + ln) * PADK + kk);
#pragma unroll
        for (int nt = 0; nt < NT; nt++) {
            bf16x8 bfr = *(const bf16x8*)(Wt + (size_t)(nt * 16 + ln) * K + kk);
#pragma unroll
            for (int rf = 0; rf < RF; rf++)
                acc[rf][nt] = __builtin_amdgcn_mfma_f32_16x16x32_bf16(af[rf], bfr, acc[rf][nt], 0, 0, 0);
        }
    }
#pragma unroll
    for (int rf = 0; rf < RF; rf++)
#pragma unroll
        for (int nt = 0; nt < NT; nt++)
#pragma unroll
            for (int r = 0; r < 4; r++) {
                int orow = row0 + wrow + rf * 16 + g * 4 + r;
                if (orow < M) out[(size_t)orow * COLS + nt * 16 + ln] = f2bf(acc[rf][nt][r]);
            }
}

// ---------------- pull-SpMM: cooperative metadata load + 4x unrolled gathers ----------------
// XCD-chunked block swizzle: grid 25000 = 8*3125 -> consecutive rows share an
// XCD's L2 and walk the col-sorted gather window together.

template <int D, bool DROP>
__global__ void spmm_bf(const int* __restrict__ row_ptr, const int2* __restrict__ cw,
                        const short* __restrict__ h,
                        const float* __restrict__ bias, const float* __restrict__ mask,
                        short* __restrict__ out, int n) {
    int bid = blockIdx.x;
    int sbid = (bid & 7) * 3125 + (bid >> 3);  // grid must be 25000
    int wid = sbid * 4 + (int)(threadIdx.x >> 6);
    int lane = threadIdx.x & 63;
    if (wid >= n) return;
    int s = row_ptr[wid], e = row_ptr[wid + 1];
    float ax = 0.f, ay = 0.f;
    int base = s;
    while (base < e) {
        int m = e - base;
        if (m > 64) m = 64;
        int2 cwv = (lane < m) ? cw[base + lane] : make_int2(0, 0);
        int j = 0;
        for (; j + 4 <= m; j += 4) {
            int c0 = __shfl(cwv.x, j);     float w0 = __uint_as_float(__shfl(cwv.y, j));
            int c1 = __shfl(cwv.x, j + 1); float w1 = __uint_as_float(__shfl(cwv.y, j + 1));
            int c2 = __shfl(cwv.x, j + 2); float w2 = __uint_as_float(__shfl(cwv.y, j + 2));
            int c3 = __shfl(cwv.x, j + 3); float w3 = __uint_as_float(__shfl(cwv.y, j + 3));
            if (D == 128) {
                unsigned u0 = *(const unsigned*)(h + (size_t)c0 * 128 + 2 * lane);
                unsigned u1 = *(const unsigned*)(h + (size_t)c1 * 128 + 2 * lane);
                unsigned u2 = *(const unsigned*)(h + (size_t)c2 * 128 + 2 * lane);
                unsigned u3 = *(const unsigned*)(h + (size_t)c3 * 128 + 2 * lane);
                ax += w0 * bflo(u0); ay += w0 * bfhi(u0);
                ax += w1 * bflo(u1); ay += w1 * bfhi(u1);
                ax += w2 * bflo(u2); ay += w2 * bfhi(u2);
                ax += w3 * bflo(u3); ay += w3 * bfhi(u3);
            } else {
                float v0 = bf2f(h[(size_t)c0 * 64 + lane]);
                float v1 = bf2f(h[(size_t)c1 * 64 + lane]);
                float v2 = bf2f(h[(size_t)c2 * 64 + lane]);
                float v3 = bf2f(h[(size_t)c3 * 64 + lane]);
                ax += w0 * v0 + w1 * v1 + w2 * v2 + w3 * v3;
            }
        }
        for (; j < m; j++) {
            int c0 = __shfl(cwv.x, j);
            float w0 = __uint_as_float(__shfl(cwv.y, j));
            if (D == 128) {
                unsigned u0 = *(const unsigned*)(h + (size_t)c0 * 128 + 2 * lane);
                ax += w0 * bflo(u0); ay += w0 * bfhi(u0);
            } else {
                ax += w0 * bf2f(h[(size_t)c0 * 64 + lane]);
            }
        }
        base += m;
    }
    if (D == 128) {
        float2 b = *(const float2*)(bias + 2 * lane);
        float ox = ax + b.x, oy = ay + b.y;
        ox = ox > 0.f ? ox : SLOPE_ * ox;
        oy = oy > 0.f ? oy : SLOPE_ * oy;
        if (DROP) {
            float2 m2 = *(const float2*)(mask + (size_t)wid * 128 + 2 * lane);
            ox *= m2.x;
            oy *= m2.y;
        }
        unsigned ov = (unsigned)(unsigned short)f2bf(ox) |
                      ((unsigned)(unsigned short)f2bf(oy) << 16);
        *(unsigned*)(out + (size_t)wid * 128 + 2 * lane) = ov;
    } else {
        float o = ax + bias[lane];
        o = o > 0.f ? o : SLOPE_ * o;
        out[(size_t)wid * 64 + lane] = f2bf(o);
    }
}

// ---------------- fused classifier: out = lrelu(h@W3+b3)@W4 + b4 (h bf16) ----------------

__global__ void clf_k(const short* __restrict__ h, const float* __restrict__ W3,
                      const float* __restrict__ b3, const float* __restrict__ W4,
                      const float* __restrict__ b4, float* __restrict__ out) {
    __shared__ float W3s[64][32];
    __shared__ float W4s[32][16];
    __shared__ float b3s[32], b4s[16];
    __shared__ float hs[32][64];
    __shared__ float t4[32][33];  // pad
    int t = threadIdx.x;
    for (int l = t; l < 64 * 32; l += 256) W3s[l / 32][l % 32] = W3[l];
    for (int l = t; l < 32 * 16; l += 256) W4s[l / 16][l % 16] = W4[l];
    if (t < 32) b3s[t] = b3[t];
    if (t < 16) b4s[t] = b4[t];
    int row0 = blockIdx.x * 32;
    {
        bf16x8 v = *(const bf16x8*)(h + (size_t)row0 * 64 + t * 8);
        int r = t >> 3, c0 = (t & 7) << 3;
#pragma unroll
        for (int j = 0; j < 8; j++) hs[r][c0 + j] = bf2f(v[j]);
    }
    __syncthreads();
    for (int l = t; l < 1024; l += 256) {
        int r = l / 32, c = l % 32;
        float a = b3s[c];
#pragma unroll 8
        for (int k = 0; k < 64; k++) a += hs[r][k] * W3s[k][c];
        t4[r][c] = a > 0.f ? a : SLOPE_ * a;
    }
    __syncthreads();
    for (int l = t; l < 512; l += 256) {
        int r = l / 16, c = l % 16;
        float a = b4s[c];
#pragma unroll
        for (int k = 0; k < 32; k++) a += t4[r][k] * W4s[k][c];
        out[(size_t)(row0 + r) * 16 + c] = a;
    }
}

// ---------------- launch ----------------

extern "C" void kernel_launch(void* const* d_in, const int* in_sizes, int n_in,
                              void* d_out, int out_size, void* d_ws, size_t ws_size,
                              hipStream_t stream) {
    const float* x = (const float*)d_in[0];
    const int* row = (const int*)d_in[1];
    const int* col = (const int*)d_in[2];
    const float* ew = (const float*)d_in[3];
    const float* W1 = (const float*)d_in[4];
    const float* b1 = (const float*)d_in[5];
    const float* W2 = (const float*)d_in[6];
    const float* b2 = (const float*)d_in[7];
    const float* W3 = (const float*)d_in[8];
    const float* b3 = (const float*)d_in[9];
    const float* W4 = (const float*)d_in[10];
    const float* b4 = (const float*)d_in[11];
    const float* mask = (const float*)d_in[12];
    float* out = (float*)d_out;

    const int N = N_NODES, E = N_EDGES;

    short* h0 = (short*)d_ws;              // N*128 bf16 (gemm1 out)
    short* h1 = h0 + (size_t)N * 128;      // N*128 bf16 (spmm1 out)
    short* h2 = h1 + (size_t)N * 128;      // N*64  bf16 (gemm2 out)
    short* h3 = h2 + (size_t)N * 64;       // N*64  bf16 (spmm2 out)
    short* Wt1 = h3 + (size_t)N * 64;      // 128*256 bf16
    short* Wt2 = Wt1 + 128 * 256;          // 64*128 bf16
    int* row_ptr = (int*)(Wt2 + 64 * 128); // N+1
    int* cur = row_ptr + N + 1;            // NBK
    int2* cw = (int2*)(cur + NBK + 3);     // E int2 (8B-aligned by layout)
    int2* binned = (int2*)h0;              // NBK*BCAP int2 = 14.5MB, aliases h0
                                           // (consumed by passB before gemm1 writes h0)

    hipMemsetAsync(cur, 0, NBK * sizeof(int), stream);
    passA_k<<<BINBLK, 256, 0, stream>>>(row, col, ew, cur, binned);
    passB_k<<<NBK, 512, 0, stream>>>(binned, cur, cw, row_ptr);
    prep_k<<<160, 256, 0, stream>>>(W1, W2, Wt1, Wt2);

    gemm_mfma<256, 128, false, 64><<<(N + 63) / 64, 256, 0, stream>>>(x, Wt1, h0, N);
    spmm_bf<128, true><<<25000, 256, 0, stream>>>(row_ptr, cw, h0, b1, mask, h1, N);
    gemm_mfma<128, 64, true, 128><<<(N + 127) / 128, 256, 0, stream>>>(h1, Wt2, h2, N);
    spmm_bf<64, false><<<25000, 256, 0, stream>>>(row_ptr, cw, h2, b2, nullptr, h3, N);
    clf_k<<<N / 32, 256, 0, stream>>>(h3, W3, b3, W4, b4, out);
}

// Round 7
// 256.529 us; speedup vs baseline: 4.5603x; 1.1909x over previous
//
#include <hip/hip_runtime.h>
#include <hip/hip_bf16.h>

#define N_NODES 100000
#define N_EDGES 1600000
#define SLOPE_ 0.2f
#define NBK 196      // row buckets of 512
#define BCAP 9216    // bucket capacity (mean 8192 + 11 sigma)
#define NCB 25       // col buckets (col>>12), 25*4096 >= 100000
#define KEYS (512 * NCB)
#define BINBLK 256   // binning blocks; chunk = E/BINBLK = 6250

typedef __attribute__((ext_vector_type(8))) short bf16x8;
typedef __attribute__((ext_vector_type(4))) float f32x4;

__device__ __forceinline__ short f2bf(float f) {
    __hip_bfloat16 h = __float2bfloat16(f);
    return *reinterpret_cast<short*>(&h);
}
__device__ __forceinline__ float bflo(unsigned u) { return __uint_as_float(u << 16); }
__device__ __forceinline__ float bfhi(unsigned u) { return __uint_as_float(u & 0xFFFF0000u); }
__device__ __forceinline__ float bf2f(short s) {
    return __uint_as_float(((unsigned)(unsigned short)s) << 16);
}

// ---------------- CSR build, bucketed ----------------
// passA: block-aggregated binning by row-bucket (row>>9): LDS histogram ->
// 1 global atomic per (block,bucket) -> LDS-offset scatter. 196 dense write
// fronts -> write amplification ~1, no global atomic contention.

__global__ void passA_k(const int* __restrict__ row, const int* __restrict__ col,
                        const float* __restrict__ ew, int* __restrict__ cur,
                        int2* __restrict__ binned) {
    __shared__ int hist[NBK], base[NBK], off[NBK];
    int t = threadIdx.x;
    const int chunk = N_EDGES / BINBLK;  // 6250
    int e0 = blockIdx.x * chunk;
    for (int i = t; i < NBK; i += 256) { hist[i] = 0; off[i] = 0; }
    __syncthreads();
    for (int i = t; i < chunk; i += 256) {
        int b = row[e0 + i] >> 9;
        atomicAdd(&hist[b], 1);            // LDS atomic
    }
    __syncthreads();
    for (int i = t; i < NBK; i += 256)
        base[i] = atomicAdd(&cur[i], hist[i]);  // 196 global atomics per block
    __syncthreads();
    for (int i = t; i < chunk; i += 256) {
        int e = e0 + i;
        int r = row[e], c = col[e];
        int b = r >> 9;
        int p = base[b] + atomicAdd(&off[b], 1);  // LDS atomic
        if (p < BCAP)
            binned[(size_t)b * BCAP + p] =
                make_int2(((r & 511) << 17) | c, __float_as_int(ew[e]));
    }
}

// passB: one block per bucket. LDS counting sort by key = localrow*NCB + col>>12.
// Emits final cw (writes within a 64KB window -> L2-absorbed) and row_ptr.

__global__ void __launch_bounds__(512) passB_k(const int2* __restrict__ binned,
                                               const int* __restrict__ cur,
                                               int2* __restrict__ cw,
                                               int* __restrict__ row_ptr) {
    __shared__ int hist[KEYS];
    __shared__ int offs[KEYS];
    __shared__ int ssum[512];
    __shared__ int bexc[256];
    int t = threadIdx.x, b = blockIdx.x;
    const int2* src = binned + (size_t)b * BCAP;
    int cnt = cur[b];
    if (cnt > BCAP) cnt = BCAP;

    // exclusive scan of bucket counts -> global base of this bucket
    if (t < 256) bexc[t] = (t < NBK) ? min(cur[t], BCAP) : 0;
    __syncthreads();
    for (int off2 = 1; off2 < 256; off2 <<= 1) {
        int v = (t < 256 && t >= off2) ? bexc[t - off2] : 0;
        __syncthreads();
        if (t < 256) bexc[t] += v;
        __syncthreads();
    }
    int gbase = bexc[b] - cnt;

    for (int i = t; i < KEYS; i += 512) hist[i] = 0;
    __syncthreads();

    // phase 1: histogram keys
    for (int i = t; i < cnt; i += 512) {
        int2 v = src[i];
        int c = v.x & 0x1FFFF, lr = v.x >> 17;
        atomicAdd(&hist[lr * NCB + (c >> 12)], 1);
    }
    __syncthreads();

    // scan: thread t owns localrow t's NCB keys
    int loc[NCB];
    int tot = 0;
#pragma unroll
    for (int j = 0; j < NCB; j++) {
        loc[j] = tot;
        tot += hist[t * NCB + j];
    }
    ssum[t] = tot;
    __syncthreads();
    for (int off2 = 1; off2 < 512; off2 <<= 1) {
        int v = (t >= off2) ? ssum[t - off2] : 0;
        __syncthreads();
        ssum[t] += v;
        __syncthreads();
    }
    int base = ssum[t] - tot;
#pragma unroll
    for (int j = 0; j < NCB; j++) offs[t * NCB + j] = base + loc[j];

    // row_ptr: start of global row (b*512 + t); entry N gets E.
    int grow = b * 512 + t;
    if (grow <= N_NODES) row_ptr[grow] = gbase + base;
    __syncthreads();

    // phase 2: scatter into final CSR (64KB destination window)
    for (int i = t; i < cnt; i += 512) {
        int2 v = src[i];
        int c = v.x & 0x1FFFF, lr = v.x >> 17;
        int p = gbase + atomicAdd(&offs[lr * NCB + (c >> 12)], 1);
        cw[p] = make_int2(c, v.y);
    }
}

// ---------------- weight prep ----------------
// Bp layout: chunk c = ((ks*4+g)*NT + nt)*16 + ln holds 8 bf16 of
// B[col = nt*16+ln][k = ks*32+g*8 .. +7]  -> gemm stages it contiguously and
// each wave's ds_read_b128 is a 256B-contiguous 16-lane read (2-way = free).

__global__ void prep_k(const float* __restrict__ W1, const float* __restrict__ W2,
                       short* __restrict__ Bp1, short* __restrict__ Bp2) {
    int i = blockIdx.x * 256 + threadIdx.x;  // grid 20 blocks = 5120 threads
    if (i < 4096) {  // gemm1: K=256, NT=8
        int ln = i & 15, nt = (i >> 4) & 7, g = (i >> 7) & 3, ks = i >> 9;
        int n = nt * 16 + ln, k0 = ks * 32 + g * 8;
        bf16x8 v;
#pragma unroll
        for (int j = 0; j < 8; j++) v[j] = f2bf(W1[(k0 + j) * 128 + n]);
        *(bf16x8*)(Bp1 + (size_t)i * 8) = v;
    } else if (i < 5120) {  // gemm2: K=128, NT=4
        int c = i - 4096;
        int ln = c & 15, nt = (c >> 4) & 3, g = (c >> 6) & 3, ks = c >> 8;
        int n = nt * 16 + ln, k0 = ks * 32 + g * 8;
        bf16x8 v;
#pragma unroll
        for (int j = 0; j < 8; j++) v[j] = f2bf(W2[(k0 + j) * 64 + n]);
        *(bf16x8*)(Bp2 + (size_t)c * 8) = v;
    }
}

// ---------------- skinny MFMA GEMM: out[M][COLS](bf16) = A[M][K] @ W ----------------
// B panel resident in LDS (staged once, fragment-ordered). A streamed from
// global straight to registers (16 rows x 128B contiguous per frag -> coalesced).
// 8 waves x 32 rows = 256 rows/block; grid 391 -> all blocks co-resident
// (2/CU at 64KB LDS); no barriers after the one-shot B stage.

template <int K, int COLS, bool ABF16>
__global__ __launch_bounds__(512) void gemm_p(const void* __restrict__ Ap,
                                              const short* __restrict__ Bp,
                                              short* __restrict__ out, int M) {
    constexpr int NT = COLS / 16;
    constexpr int NKS = K / 32;
    __shared__ short Bs[K * COLS];
    int t = threadIdx.x;
    for (int i = t; i < K * COLS / 8; i += 512)
        *(bf16x8*)(Bs + (size_t)i * 8) = *(const bf16x8*)(Bp + (size_t)i * 8);
    __syncthreads();

    int l = t & 63, wv = t >> 6;
    int ln = l & 15, g = l >> 4;           // g in 0..3
    int row0 = blockIdx.x * 256 + wv * 32; // wave owns 32 rows
    int r0 = row0 + ln, r1 = row0 + 16 + ln;
    int cr0 = min(r0, M - 1), cr1 = min(r1, M - 1);

    f32x4 acc[2][NT];
#pragma unroll
    for (int rf = 0; rf < 2; rf++)
#pragma unroll
        for (int nt = 0; nt < NT; nt++) acc[rf][nt] = (f32x4){0.f, 0.f, 0.f, 0.f};

#pragma unroll
    for (int ks = 0; ks < NKS; ks++) {
        int kk = ks * 32 + g * 8;
        bf16x8 a0, a1;
        if constexpr (ABF16) {
            a0 = *(const bf16x8*)((const short*)Ap + (size_t)cr0 * K + kk);
            a1 = *(const bf16x8*)((const short*)Ap + (size_t)cr1 * K + kk);
        } else {
            const float* p0 = (const float*)Ap + (size_t)cr0 * K + kk;
            const float* p1 = (const float*)Ap + (size_t)cr1 * K + kk;
            float4 u0 = *(const float4*)p0;
            float4 u1 = *(const float4*)(p0 + 4);
            float4 v0 = *(const float4*)p1;
            float4 v1 = *(const float4*)(p1 + 4);
            a0[0] = f2bf(u0.x); a0[1] = f2bf(u0.y); a0[2] = f2bf(u0.z); a0[3] = f2bf(u0.w);
            a0[4] = f2bf(u1.x); a0[5] = f2bf(u1.y); a0[6] = f2bf(u1.z); a0[7] = f2bf(u1.w);
            a1[0] = f2bf(v0.x); a1[1] = f2bf(v0.y); a1[2] = f2bf(v0.z); a1[3] = f2bf(v0.w);
            a1[4] = f2bf(v1.x); a1[5] = f2bf(v1.y); a1[6] = f2bf(v1.z); a1[7] = f2bf(v1.w);
        }
#pragma unroll
        for (int nt = 0; nt < NT; nt++) {
            bf16x8 b = *(const bf16x8*)(Bs + (size_t)((((ks * 4 + g) * NT + nt) * 16 + ln)) * 8);
            acc[0][nt] = __builtin_amdgcn_mfma_f32_16x16x32_bf16(a0, b, acc[0][nt], 0, 0, 0);
            acc[1][nt] = __builtin_amdgcn_mfma_f32_16x16x32_bf16(a1, b, acc[1][nt], 0, 0, 0);
        }
    }
#pragma unroll
    for (int rf = 0; rf < 2; rf++)
#pragma unroll
        for (int nt = 0; nt < NT; nt++)
#pragma unroll
            for (int r = 0; r < 4; r++) {
                int orow = row0 + rf * 16 + g * 4 + r;
                if (orow < M) out[(size_t)orow * COLS + nt * 16 + ln] = f2bf(acc[rf][nt][r]);
            }
}

// ---------------- pull-SpMM: cooperative metadata load + 4x unrolled gathers ----------------
// XCD-chunked block swizzle: grid 25000 = 8*3125.

template <int D, bool DROP>
__global__ void spmm_bf(const int* __restrict__ row_ptr, const int2* __restrict__ cw,
                        const short* __restrict__ h,
                        const float* __restrict__ bias, const float* __restrict__ mask,
                        short* __restrict__ out, int n) {
    int bid = blockIdx.x;
    int sbid = (bid & 7) * 3125 + (bid >> 3);  // grid must be 25000
    int wid = sbid * 4 + (int)(threadIdx.x >> 6);
    int lane = threadIdx.x & 63;
    if (wid >= n) return;
    int s = row_ptr[wid], e = row_ptr[wid + 1];
    float ax = 0.f, ay = 0.f;
    int base = s;
    while (base < e) {
        int m = e - base;
        if (m > 64) m = 64;
        int2 cwv = (lane < m) ? cw[base + lane] : make_int2(0, 0);
        int j = 0;
        for (; j + 4 <= m; j += 4) {
            int c0 = __shfl(cwv.x, j);     float w0 = __uint_as_float(__shfl(cwv.y, j));
            int c1 = __shfl(cwv.x, j + 1); float w1 = __uint_as_float(__shfl(cwv.y, j + 1));
            int c2 = __shfl(cwv.x, j + 2); float w2 = __uint_as_float(__shfl(cwv.y, j + 2));
            int c3 = __shfl(cwv.x, j + 3); float w3 = __uint_as_float(__shfl(cwv.y, j + 3));
            if (D == 128) {
                unsigned u0 = *(const unsigned*)(h + (size_t)c0 * 128 + 2 * lane);
                unsigned u1 = *(const unsigned*)(h + (size_t)c1 * 128 + 2 * lane);
                unsigned u2 = *(const unsigned*)(h + (size_t)c2 * 128 + 2 * lane);
                unsigned u3 = *(const unsigned*)(h + (size_t)c3 * 128 + 2 * lane);
                ax += w0 * bflo(u0); ay += w0 * bfhi(u0);
                ax += w1 * bflo(u1); ay += w1 * bfhi(u1);
                ax += w2 * bflo(u2); ay += w2 * bfhi(u2);
                ax += w3 * bflo(u3); ay += w3 * bfhi(u3);
            } else {
                float v0 = bf2f(h[(size_t)c0 * 64 + lane]);
                float v1 = bf2f(h[(size_t)c1 * 64 + lane]);
                float v2 = bf2f(h[(size_t)c2 * 64 + lane]);
                float v3 = bf2f(h[(size_t)c3 * 64 + lane]);
                ax += w0 * v0 + w1 * v1 + w2 * v2 + w3 * v3;
            }
        }
        for (; j < m; j++) {
            int c0 = __shfl(cwv.x, j);
            float w0 = __uint_as_float(__shfl(cwv.y, j));
            if (D == 128) {
                unsigned u0 = *(const unsigned*)(h + (size_t)c0 * 128 + 2 * lane);
                ax += w0 * bflo(u0); ay += w0 * bfhi(u0);
            } else {
                ax += w0 * bf2f(h[(size_t)c0 * 64 + lane]);
            }
        }
        base += m;
    }
    if (D == 128) {
        float2 b = *(const float2*)(bias + 2 * lane);
        float ox = ax + b.x, oy = ay + b.y;
        ox = ox > 0.f ? ox : SLOPE_ * ox;
        oy = oy > 0.f ? oy : SLOPE_ * oy;
        if (DROP) {
            float2 m2 = *(const float2*)(mask + (size_t)wid * 128 + 2 * lane);
            ox *= m2.x;
            oy *= m2.y;
        }
        unsigned ov = (unsigned)(unsigned short)f2bf(ox) |
                      ((unsigned)(unsigned short)f2bf(oy) << 16);
        *(unsigned*)(out + (size_t)wid * 128 + 2 * lane) = ov;
    } else {
        float o = ax + bias[lane];
        o = o > 0.f ? o : SLOPE_ * o;
        out[(size_t)wid * 64 + lane] = f2bf(o);
    }
}

// ---------------- fused classifier: out = lrelu(h@W3+b3)@W4 + b4 (h bf16) ----------------

__global__ void clf_k(const short* __restrict__ h, const float* __restrict__ W3,
                      const float* __restrict__ b3, const float* __restrict__ W4,
                      const float* __restrict__ b4, float* __restrict__ out) {
    __shared__ float W3s[64][32];
    __shared__ float W4s[32][16];
    __shared__ float b3s[32], b4s[16];
    __shared__ float hs[32][64];
    __shared__ float t4[32][33];  // pad
    int t = threadIdx.x;
    for (int l = t; l < 64 * 32; l += 256) W3s[l / 32][l % 32] = W3[l];
    for (int l = t; l < 32 * 16; l += 256) W4s[l / 16][l % 16] = W4[l];
    if (t < 32) b3s[t] = b3[t];
    if (t < 16) b4s[t] = b4[t];
    int row0 = blockIdx.x * 32;
    {
        bf16x8 v = *(const bf16x8*)(h + (size_t)row0 * 64 + t * 8);
        int r = t >> 3, c0 = (t & 7) << 3;
#pragma unroll
        for (int j = 0; j < 8; j++) hs[r][c0 + j] = bf2f(v[j]);
    }
    __syncthreads();
    for (int l = t; l < 1024; l += 256) {
        int r = l / 32, c = l % 32;
        float a = b3s[c];
#pragma unroll 8
        for (int k = 0; k < 64; k++) a += hs[r][k] * W3s[k][c];
        t4[r][c] = a > 0.f ? a : SLOPE_ * a;
    }
    __syncthreads();
    for (int l = t; l < 512; l += 256) {
        int r = l / 16, c = l % 16;
        float a = b4s[c];
#pragma unroll
        for (int k = 0; k < 32; k++) a += t4[r][k] * W4s[k][c];
        out[(size_t)(row0 + r) * 16 + c] = a;
    }
}

// ---------------- launch ----------------

extern "C" void kernel_launch(void* const* d_in, const int* in_sizes, int n_in,
                              void* d_out, int out_size, void* d_ws, size_t ws_size,
                              hipStream_t stream) {
    const float* x = (const float*)d_in[0];
    const int* row = (const int*)d_in[1];
    const int* col = (const int*)d_in[2];
    const float* ew = (const float*)d_in[3];
    const float* W1 = (const float*)d_in[4];
    const float* b1 = (const float*)d_in[5];
    const float* W2 = (const float*)d_in[6];
    const float* b2 = (const float*)d_in[7];
    const float* W3 = (const float*)d_in[8];
    const float* b3 = (const float*)d_in[9];
    const float* W4 = (const float*)d_in[10];
    const float* b4 = (const float*)d_in[11];
    const float* mask = (const float*)d_in[12];
    float* out = (float*)d_out;

    const int N = N_NODES, E = N_EDGES;

    short* h0 = (short*)d_ws;              // N*128 bf16 (gemm1 out)
    short* h1 = h0 + (size_t)N * 128;      // N*128 bf16 (spmm1 out)
    short* h2 = h1 + (size_t)N * 128;      // N*64  bf16 (gemm2 out)
    short* h3 = h2 + (size_t)N * 64;       // N*64  bf16 (spmm2 out)
    short* Bp1 = h3 + (size_t)N * 64;      // 32768 bf16 (fragment-ordered W1)
    short* Bp2 = Bp1 + 32768;              // 8192  bf16 (fragment-ordered W2)
    int* row_ptr = (int*)(Bp2 + 8192);     // N+1
    int* cur = row_ptr + N + 1;            // NBK
    int2* cw = (int2*)(cur + NBK + 3);     // E int2 (8B-aligned by layout)
    int2* binned = (int2*)h0;              // NBK*BCAP int2 = 14.5MB, aliases h0
                                           // (consumed by passB before gemm1 writes h0)

    hipMemsetAsync(cur, 0, NBK * sizeof(int), stream);
    passA_k<<<BINBLK, 256, 0, stream>>>(row, col, ew, cur, binned);
    passB_k<<<NBK, 512, 0, stream>>>(binned, cur, cw, row_ptr);
    prep_k<<<20, 256, 0, stream>>>(W1, W2, Bp1, Bp2);

    gemm_p<256, 128, false><<<(N + 255) / 256, 512, 0, stream>>>(x, Bp1, h0, N);
    spmm_bf<128, true><<<25000, 256, 0, stream>>>(row_ptr, cw, h0, b1, mask, h1, N);
    gemm_p<128, 64, true><<<(N + 255) / 256, 512, 0, stream>>>(h1, Bp2, h2, N);
    spmm_bf<64, false><<<25000, 256, 0, stream>>>(row_ptr, cw, h2, b2, nullptr, h3, N);
    clf_k<<<N / 32, 256, 0, stream>>>(h3, W3, b3, W4, b4, out);
}